// Round 12
// baseline (329.789 us; speedup 1.0000x reference)
//
#include <hip/hip_runtime.h>

// RBFolution: out[b,y,x,f] = exp(-beta[f] * (||patch||^2 - 2 patch.ccs[:,f] + ||ccs[:,f]||^2))
// x: [32,112,112,32] f32, ccs: [288,128] f32, beta: [128] f32, out: [32,110,110,128] f32
//
// R16: BARRIER-FREE main. Ledger: 7 structural variants (TLP x3, pipeline, col-split,
// chain-halving, A-hoist) all 113-137us; all share stage->barrier->compute lockstep,
// and counters show every pipe <15% busy -- the barrier phase-convergence signature.
// x is L3-resident (R11: FETCH 31.5MB < 51MB input), so LDS staging is only there for
// f32->bf16 conversion + p_sq sharing. Move both to pre-kernels:
//   pre_x:  x -> xbf (bf16 copy, 25.7MB, L3-resident) + colsum (fp32 channel sum-sq)
//   pre_psq: p_sq = 3x3 colsum sums (fp32-exact)
//   main_nb: NO LDS, NO syncthreads. B-frags straight from xbf (1KB/wave coalesced,
//            L1-hot: block B-working-set 21.5KB), A per kb, proven nt full-line stores.
// ws needs 27.6MB -> guarded; falls back to R9 kernel if ws_size too small.

typedef __attribute__((ext_vector_type(8))) short bf16x8;
typedef __attribute__((ext_vector_type(4))) float f32x4;

#define HH 112
#define WW 112
#define CC 32
#define HO 110
#define WO 110
#define NF 128
#define KD 288
#define ORPB 2         // output rows per block (main)
// R9-fallback LDS geometry
#define RPX 114
#define XP 32
#define CSP 116
#define SROWS 4

__device__ __forceinline__ unsigned short f32_to_bf16(float f) {
    unsigned u = __float_as_uint(f);
    unsigned r = u + 0x7FFFu + ((u >> 16) & 1u);   // round-to-nearest-even
    return (unsigned short)(r >> 16);
}

// --- Prologue: ccs [288][128] f32 -> ccs_t [128][288] bf16 (all blocks);
//     block 0 threads 0..127 also compute c_sq[f] = sum_d ccs[d][f]^2.
__global__ __launch_bounds__(256) void rbf_prologue(const float* __restrict__ ccs,
                                                    unsigned short* __restrict__ ccs_t,
                                                    float* __restrict__ c_sq) {
    int idx = blockIdx.x * 256 + threadIdx.x;     // 0..36863, coalesced read
    int d = idx >> 7;
    int f = idx & 127;
    ccs_t[f * KD + d] = f32_to_bf16(ccs[idx]);
    if (blockIdx.x == 0 && threadIdx.x < 128) {
        const int fc = threadIdx.x;
        float s = 0.f;
        #pragma unroll 8
        for (int dd = 0; dd < KD; ++dd) {
            float v = ccs[dd * NF + fc];
            s += v * v;
        }
        c_sq[fc] = s;
    }
}

// --- pre_x: x f32 -> xbf bf16 (same [b][row][px][c] layout) + colsum[b][row][px].
//     Block = 4 rows of one b. 4*112*8 = 3584 float4 units = 14*256 exact.
__global__ __launch_bounds__(256) void rbf_pre_x(const float* __restrict__ x,
                                                 unsigned short* __restrict__ xbf,
                                                 float* __restrict__ colsum) {
    const int t = threadIdx.x;
    const int r0 = blockIdx.x * 4;     // 0,4,...,108
    const int b  = blockIdx.y;
    #pragma unroll
    for (int p = 0; p < 14; ++p) {
        int idx = t + p * 256;
        int q = idx & 7;               // channel quarter
        int ic = idx >> 3;             // 0..447 = i*112 + col
        int col = ic % 112;
        int i = ic / 112;              // 0..3
        const size_t e = ((size_t)(b * HH + r0 + i) * WW + col) * CC + q * 4;
        const float4 v = *(const float4*)(x + e);
        unsigned short h0 = f32_to_bf16(v.x), h1 = f32_to_bf16(v.y);
        unsigned short h2 = f32_to_bf16(v.z), h3 = f32_to_bf16(v.w);
        uint2 pk;
        pk.x = (unsigned)h0 | ((unsigned)h1 << 16);
        pk.y = (unsigned)h2 | ((unsigned)h3 << 16);
        *(uint2*)(xbf + e) = pk;       // bf16, same element index -> 8B coalesced
        float part = v.x * v.x + v.y * v.y + v.z * v.z + v.w * v.w;
        part += __shfl_xor(part, 1);
        part += __shfl_xor(part, 2);
        part += __shfl_xor(part, 4);
        if (q == 0) colsum[(size_t)(b * HH + r0 + i) * WW + col] = part;
    }
}

// --- pre_psq: p_sq[b][y][px] = sum_{i,j in 3x3} colsum[b][y+i][px+j], y<110.
//     32*110*112 = 394240 = 1540*256 exact. px>=110 -> clamped garbage (masked outputs).
__global__ __launch_bounds__(256) void rbf_pre_psq(const float* __restrict__ colsum,
                                                   float* __restrict__ p_sq) {
    int idx = blockIdx.x * 256 + threadIdx.x;
    int px = idx % 112;
    int y  = (idx / 112) % 110;
    int b  = idx / (112 * 110);
    int c0 = (px > 109) ? 109 : px;    // clamp for masked px 110/111
    float s = 0.f;
    #pragma unroll
    for (int i = 0; i < 3; ++i) {
        const float* row = colsum + (size_t)(b * HH + y + i) * WW + c0;
        s += row[0] + row[1] + row[2];
    }
    p_sq[idx] = s;
}

// --- Main (barrier-free): one block per (2-row strip, b). 4 waves = 4 filter groups.
//     NO LDS, NO __syncthreads: waves free-run; B-frags from xbf (L1/L2-hot).
__global__ __launch_bounds__(256) void rbf_main_nb(const unsigned short* __restrict__ xbf,
                                                   const unsigned short* __restrict__ ccs_t,
                                                   const float* __restrict__ p_sq,
                                                   const float* __restrict__ c_sq,
                                                   const float* __restrict__ beta,
                                                   float* __restrict__ out) {
    const int t = threadIdx.x;
    const int y0 = blockIdx.x * ORPB;  // 0,2,...,108
    const int b  = blockIdx.y;         // 0..31

    const int lane  = t & 63;
    const int wave  = t >> 6;            // filter group
    const int laneM = lane & 15;
    const int quad  = lane >> 4;
    const int pl    = laneM & 1;

    const unsigned short* ap0 = ccs_t + (size_t)(wave * 32 + laneM) * KD + quad * 8;
    const unsigned short* ap1 = ap0 + 16 * KD;

    const int fb = wave * 32 + quad * 4;
    const float4 cs0 = *(const float4*)(c_sq + fb);
    const float4 cs1 = *(const float4*)(c_sq + fb + 16);
    const float4 bt0 = *(const float4*)(beta + fb);
    const float4 bt1 = *(const float4*)(beta + fb + 16);

    for (int r = 0; r < ORPB; ++r) {
        f32x4 acc[7][2];
        #pragma unroll
        for (int mi = 0; mi < 7; ++mi) {
            acc[mi][0] = (f32x4){0.f, 0.f, 0.f, 0.f};
            acc[mi][1] = (f32x4){0.f, 0.f, 0.f, 0.f};
        }

        #pragma unroll
        for (int kb = 0; kb < 9; ++kb) {     // tap (ki,kj), K=32 channels
            const int ki = kb / 3, kj = kb % 3;
            bf16x8 a0 = *(const bf16x8*)(ap0 + kb * 32);
            bf16x8 a1 = *(const bf16x8*)(ap1 + kb * 32);
            const unsigned short* brow = xbf + ((size_t)(b * HH + y0 + r + ki) * WW + laneM + kj) * CC + quad * 8;
            #pragma unroll
            for (int mi = 0; mi < 7; ++mi) {
                // B[k = quad*8+j][n = laneM]: 16B/lane, 1KB/wave coalesced from xbf.
                // px reaches 113 at row 111 -> crosses into pad/next row: masked lanes only.
                const bf16x8 bf = *(const bf16x8*)(brow + (size_t)mi * 16 * CC);
                acc[mi][0] = __builtin_amdgcn_mfma_f32_16x16x32_bf16(a0, bf, acc[mi][0], 0, 0, 0);
                acc[mi][1] = __builtin_amdgcn_mfma_f32_16x16x32_bf16(a1, bf, acc[mi][1], 0, 0, 0);
            }
        }

        // Epilogue: nt full-line stores via lane-pair swap (proven R9 combo).
        const float* psrow = p_sq + ((size_t)b * HO + y0 + r) * 112;
        float* orow = out + (size_t)((b * HO + y0 + r) * WO) * NF;
        #pragma unroll
        for (int mi = 0; mi < 7; ++mi) {
            const int px = mi * 16 + laneM;
            const float ps = psrow[px];
            f32x4 o0, o1;
            o0[0] = __expf(-bt0.x * (ps - 2.f * acc[mi][0][0] + cs0.x));
            o0[1] = __expf(-bt0.y * (ps - 2.f * acc[mi][0][1] + cs0.y));
            o0[2] = __expf(-bt0.z * (ps - 2.f * acc[mi][0][2] + cs0.z));
            o0[3] = __expf(-bt0.w * (ps - 2.f * acc[mi][0][3] + cs0.w));
            o1[0] = __expf(-bt1.x * (ps - 2.f * acc[mi][1][0] + cs1.x));
            o1[1] = __expf(-bt1.y * (ps - 2.f * acc[mi][1][1] + cs1.y));
            o1[2] = __expf(-bt1.z * (ps - 2.f * acc[mi][1][2] + cs1.z));
            o1[3] = __expf(-bt1.w * (ps - 2.f * acc[mi][1][3] + cs1.w));

            f32x4 sendv = pl ? o0 : o1;
            f32x4 recv;
            recv[0] = __shfl_xor(sendv[0], 1);
            recv[1] = __shfl_xor(sendv[1], 1);
            recv[2] = __shfl_xor(sendv[2], 1);
            recv[3] = __shfl_xor(sendv[3], 1);
            const f32x4 v1 = pl ? recv : o0;   // even-pixel full 128B line
            const f32x4 v2 = pl ? o1 : recv;   // odd-pixel full line

            const int pxe = mi * 16 + (laneM & ~1);
            float* op1 = orow + (size_t)pxe * NF + fb + pl * 16;
            if (pxe < WO)
                __builtin_nontemporal_store(v1, (f32x4*)op1);
            if (pxe + 1 < WO)
                __builtin_nontemporal_store(v2, (f32x4*)(op1 + NF));
        }
    }
}

// --- R9 fallback main (LDS path) -- used only if ws_size can't hold xbf/p_sq.
__global__ __launch_bounds__(256) void rbf_main_lds(const float* __restrict__ x,
                                                    const unsigned short* __restrict__ ccs_t,
                                                    const float* __restrict__ c_sq,
                                                    const float* __restrict__ beta,
                                                    float* __restrict__ out) {
    __shared__ unsigned short xs[SROWS * RPX * XP];
    __shared__ float colsum[SROWS * CSP];
    __shared__ float p_sq[ORPB * 112];

    const int t = threadIdx.x;
    const int y0 = blockIdx.x * ORPB;
    const int b = blockIdx.y;

    const int lane  = t & 63;
    const int wave  = t >> 6;
    const int laneM = lane & 15;
    const int quad  = lane >> 4;
    const int pl    = laneM & 1;

    #pragma unroll
    for (int p = 0; p < 14; ++p) {
        int idx = t + p * 256;
        int q = idx & 7;
        int ic = idx >> 3;
        int col = ic % 112;
        int i = ic / 112;
        const float4 v = *(const float4*)(x + ((size_t)(b * HH + y0 + i) * WW + col) * CC + q * 4);
        unsigned short h0 = f32_to_bf16(v.x), h1 = f32_to_bf16(v.y);
        unsigned short h2 = f32_to_bf16(v.z), h3 = f32_to_bf16(v.w);
        uint2 pk;
        pk.x = (unsigned)h0 | ((unsigned)h1 << 16);
        pk.y = (unsigned)h2 | ((unsigned)h3 << 16);
        *(uint2*)(&xs[(i * RPX + col) * XP + q * 4]) = pk;
        float part = v.x * v.x + v.y * v.y + v.z * v.z + v.w * v.w;
        part += __shfl_xor(part, 1);
        part += __shfl_xor(part, 2);
        part += __shfl_xor(part, 4);
        if (q == 0) colsum[i * CSP + col] = part;
    }
    __syncthreads();

    if (t < ORPB * 112) {
        int r = t / 112;
        int c = t - r * 112;
        float s = 0.f;
        #pragma unroll
        for (int i = 0; i < 3; ++i)
            #pragma unroll
            for (int j = 0; j < 3; ++j)
                s += colsum[(r + i) * CSP + c + j];
        p_sq[t] = s;
    }
    __syncthreads();

    const unsigned short* ap0 = ccs_t + (size_t)(wave * 32 + laneM) * KD + quad * 8;
    const unsigned short* ap1 = ap0 + 16 * KD;
    const int fb = wave * 32 + quad * 4;
    const float4 cs0 = *(const float4*)(c_sq + fb);
    const float4 cs1 = *(const float4*)(c_sq + fb + 16);
    const float4 bt0 = *(const float4*)(beta + fb);
    const float4 bt1 = *(const float4*)(beta + fb + 16);

    for (int r = 0; r < ORPB; ++r) {
        f32x4 acc[7][2];
        #pragma unroll
        for (int mi = 0; mi < 7; ++mi) {
            acc[mi][0] = (f32x4){0.f, 0.f, 0.f, 0.f};
            acc[mi][1] = (f32x4){0.f, 0.f, 0.f, 0.f};
        }
        #pragma unroll
        for (int kb = 0; kb < 9; ++kb) {
            const int ki = kb / 3, kj = kb % 3;
            bf16x8 a0 = *(const bf16x8*)(ap0 + kb * 32);
            bf16x8 a1 = *(const bf16x8*)(ap1 + kb * 32);
            #pragma unroll
            for (int mi = 0; mi < 7; ++mi) {
                const bf16x8 bf = *(const bf16x8*)(&xs[((r + ki) * RPX + mi * 16 + laneM + kj) * XP + quad * 8]);
                acc[mi][0] = __builtin_amdgcn_mfma_f32_16x16x32_bf16(a0, bf, acc[mi][0], 0, 0, 0);
                acc[mi][1] = __builtin_amdgcn_mfma_f32_16x16x32_bf16(a1, bf, acc[mi][1], 0, 0, 0);
            }
        }
        float* orow = out + (size_t)((b * HO + y0 + r) * WO) * NF;
        #pragma unroll
        for (int mi = 0; mi < 7; ++mi) {
            const int px = mi * 16 + laneM;
            const float ps = p_sq[r * 112 + px];
            f32x4 o0, o1;
            o0[0] = __expf(-bt0.x * (ps - 2.f * acc[mi][0][0] + cs0.x));
            o0[1] = __expf(-bt0.y * (ps - 2.f * acc[mi][0][1] + cs0.y));
            o0[2] = __expf(-bt0.z * (ps - 2.f * acc[mi][0][2] + cs0.z));
            o0[3] = __expf(-bt0.w * (ps - 2.f * acc[mi][0][3] + cs0.w));
            o1[0] = __expf(-bt1.x * (ps - 2.f * acc[mi][1][0] + cs1.x));
            o1[1] = __expf(-bt1.y * (ps - 2.f * acc[mi][1][1] + cs1.y));
            o1[2] = __expf(-bt1.z * (ps - 2.f * acc[mi][1][2] + cs1.z));
            o1[3] = __expf(-bt1.w * (ps - 2.f * acc[mi][1][3] + cs1.w));
            f32x4 sendv = pl ? o0 : o1;
            f32x4 recv;
            recv[0] = __shfl_xor(sendv[0], 1);
            recv[1] = __shfl_xor(sendv[1], 1);
            recv[2] = __shfl_xor(sendv[2], 1);
            recv[3] = __shfl_xor(sendv[3], 1);
            const f32x4 v1 = pl ? recv : o0;
            const f32x4 v2 = pl ? o1 : recv;
            const int pxe = mi * 16 + (laneM & ~1);
            float* op1 = orow + (size_t)pxe * NF + fb + pl * 16;
            if (pxe < WO)
                __builtin_nontemporal_store(v1, (f32x4*)op1);
            if (pxe + 1 < WO)
                __builtin_nontemporal_store(v2, (f32x4*)(op1 + NF));
        }
    }
}

extern "C" void kernel_launch(void* const* d_in, const int* in_sizes, int n_in,
                              void* d_out, int out_size, void* d_ws, size_t ws_size,
                              hipStream_t stream) {
    const float* x    = (const float*)d_in[0];
    const float* ccs  = (const float*)d_in[1];
    const float* beta = (const float*)d_in[2];
    float* out = (float*)d_out;

    // ws layout (256B-aligned sections)
    constexpr size_t OFF_CCS_T = 0;                       // 128*288*2 = 73728
    constexpr size_t OFF_CSQ   = 73728;                   // 512
    constexpr size_t OFF_XBF   = 74240;                   // 25,690,112 (+256 pad)
    constexpr size_t OFF_CS    = 25764608;                // colsum 32*112*112*4 = 1,605,632
    constexpr size_t OFF_PSQ   = 27370240;                // 32*110*112*4 = 1,576,960
    constexpr size_t WS_NEED   = 28947200;

    unsigned short* ccs_t = (unsigned short*)((char*)d_ws + OFF_CCS_T);
    float* c_sq = (float*)((char*)d_ws + OFF_CSQ);

    rbf_prologue<<<144, 256, 0, stream>>>(ccs, ccs_t, c_sq);

    if (ws_size >= WS_NEED) {
        unsigned short* xbf = (unsigned short*)((char*)d_ws + OFF_XBF);
        float* colsum = (float*)((char*)d_ws + OFF_CS);
        float* p_sq   = (float*)((char*)d_ws + OFF_PSQ);
        rbf_pre_x<<<dim3(28, 32), 256, 0, stream>>>(x, xbf, colsum);
        rbf_pre_psq<<<1540, 256, 0, stream>>>(colsum, p_sq);
        rbf_main_nb<<<dim3(55, 32), 256, 0, stream>>>(xbf, ccs_t, p_sq, c_sq, beta, out);
    } else {
        rbf_main_lds<<<dim3(55, 32), 256, 0, stream>>>(x, ccs_t, c_sq, beta, out);
    }
}

// Round 13
// 274.155 us; speedup vs baseline: 1.2029x; 1.2029x over previous
//
#include <hip/hip_runtime.h>

// RBFolution: out[b,y,x,f] = exp(-beta[f] * (||patch||^2 - 2 patch.ccs[:,f] + ||ccs[:,f]||^2))
// x: [32,112,112,32] f32, ccs: [288,128] f32, beta: [128] f32, out: [32,110,110,128] f32
//
// bf16 MFMA implicit GEMM; p_sq/c_sq fp32-exact (only cross term bf16, err ~1e-5).
// R17 = R9 RESTORED (champion, 262.3us total). Session ledger:
//  WIN : full-128B-line nt stores via lane-pair swap (R8->R9, WRITE 299->194MB == output)
//  LOSS: cached full-line (R13, L2/L3 pollution evicts x), nt partial-line (R7),
//        ORPB=1/4/8 (R12/R10/R11), column-split (R14), 8-wave chain-halve (R15),
//        launch-bounds TLP (R5/R8), A-hoist (R10), barrier-free+pre-kernels (R16).
//  Main is empirically bracketed at 113-137us across 9 structures; only store-burst
//  linearity ever moved it. Traffic solved: WRITE==output, FETCH~1.5x input (L3-held).
// ORPB=2, SROWS=4, 31.2KB LDS, 1760 blocks, nt+full-line epilogue.

typedef __attribute__((ext_vector_type(8))) short bf16x8;
typedef __attribute__((ext_vector_type(4))) float f32x4;

#define HH 112
#define WW 112
#define CC 32
#define HO 110
#define WO 110
#define NF 128
#define KD 288
#define RPX 114        // pixels per staged row (reads reach px 113)
#define XP 32          // bf16 elems per pixel (64 B)
#define CSP 116        // colsum row pitch (reads reach col 113)
#define ORPB 2         // output rows per block
#define SROWS 4        // staged input rows per block

__device__ __forceinline__ unsigned short f32_to_bf16(float f) {
    unsigned u = __float_as_uint(f);
    unsigned r = u + 0x7FFFu + ((u >> 16) & 1u);   // round-to-nearest-even
    return (unsigned short)(r >> 16);
}

// --- Prologue: ccs [288][128] f32 -> ccs_t [128][288] bf16 (all blocks);
//     block 0 threads 0..127 also compute c_sq[f] = sum_d ccs[d][f]^2.
__global__ __launch_bounds__(256) void rbf_prologue(const float* __restrict__ ccs,
                                                    unsigned short* __restrict__ ccs_t,
                                                    float* __restrict__ c_sq) {
    int idx = blockIdx.x * 256 + threadIdx.x;     // 0..36863, coalesced read
    int d = idx >> 7;
    int f = idx & 127;
    ccs_t[f * KD + d] = f32_to_bf16(ccs[idx]);
    if (blockIdx.x == 0 && threadIdx.x < 128) {
        const int fc = threadIdx.x;
        float s = 0.f;
        #pragma unroll 8
        for (int dd = 0; dd < KD; ++dd) {
            float v = ccs[dd * NF + fc];
            s += v * v;
        }
        c_sq[fc] = s;
    }
}

// --- Main: one block per (2-row strip, b). 2 output rows, 4 staged input rows.
__global__ __launch_bounds__(256) void rbf_main(const float* __restrict__ x,
                                                const unsigned short* __restrict__ ccs_t,
                                                const float* __restrict__ c_sq,
                                                const float* __restrict__ beta,
                                                float* __restrict__ out) {
    __shared__ unsigned short xs[SROWS * RPX * XP];   // 29184 B
    __shared__ float colsum[SROWS * CSP];             // 1856 B
    __shared__ float p_sq[ORPB * 112];                // 896 B -> 31.2 KB total

    const int t = threadIdx.x;
    const int y0 = blockIdx.x * ORPB;  // 0,2,...,108
    const int b = blockIdx.y;          // 0..31

    const int lane  = t & 63;
    const int wave  = t >> 6;            // 4 waves x 32 filters
    const int laneM = lane & 15;
    const int quad  = lane >> 4;
    const int pl    = laneM & 1;         // pair parity for full-line stores

    // Stage x[y0..y0+3][0..111][0..31] -> LDS bf16; colsum from fp32 (exact p_sq).
    // 3584 float4 units = 14 * 256 exactly (no tail). y0+3 <= 111 always (no clamp).
    #pragma unroll
    for (int p = 0; p < 14; ++p) {
        int idx = t + p * 256;
        int q = idx & 7;              // channel quarter (4 floats)
        int ic = idx >> 3;            // 0..447 = i*112 + col
        int col = ic % 112;
        int i = ic / 112;
        const float4 v = *(const float4*)(x + ((size_t)(b * HH + y0 + i) * WW + col) * CC + q * 4);
        unsigned short h0 = f32_to_bf16(v.x), h1 = f32_to_bf16(v.y);
        unsigned short h2 = f32_to_bf16(v.z), h3 = f32_to_bf16(v.w);
        uint2 pk;
        pk.x = (unsigned)h0 | ((unsigned)h1 << 16);
        pk.y = (unsigned)h2 | ((unsigned)h3 << 16);
        *(uint2*)(&xs[(i * RPX + col) * XP + q * 4]) = pk;   // 8B, contiguous per wave
        float part = v.x * v.x + v.y * v.y + v.z * v.z + v.w * v.w;
        part += __shfl_xor(part, 1);
        part += __shfl_xor(part, 2);
        part += __shfl_xor(part, 4);
        if (q == 0) colsum[i * CSP + col] = part;   // stride CSP
    }
    __syncthreads();

    if (t < ORPB * 112) {   // 224 threads
        int r = t / 112;
        int c = t - r * 112;
        float s = 0.f;
        #pragma unroll
        for (int i = 0; i < 3; ++i)
            #pragma unroll
            for (int j = 0; j < 3; ++j)
                s += colsum[(r + i) * CSP + c + j];   // c>=110: in-pitch garbage -> masked px only
        p_sq[t] = s;
    }
    __syncthreads();

    // A = ccs (M = filters): lane's filter-in-tile = laneM
    const unsigned short* ap0 = ccs_t + (size_t)(wave * 32 + laneM) * KD + quad * 8;
    const unsigned short* ap1 = ap0 + 16 * KD;

    // per-lane 4 consecutive filters (rows of D): f = wave*32 + ft*16 + quad*4 + e
    const int fb = wave * 32 + quad * 4;
    const float4 cs0 = *(const float4*)(c_sq + fb);
    const float4 cs1 = *(const float4*)(c_sq + fb + 16);
    const float4 bt0 = *(const float4*)(beta + fb);
    const float4 bt1 = *(const float4*)(beta + fb + 16);

    for (int r = 0; r < ORPB; ++r) {
        f32x4 acc[7][2];
        #pragma unroll
        for (int mi = 0; mi < 7; ++mi) {
            acc[mi][0] = (f32x4){0.f, 0.f, 0.f, 0.f};
            acc[mi][1] = (f32x4){0.f, 0.f, 0.f, 0.f};
        }

        #pragma unroll
        for (int kb = 0; kb < 9; ++kb) {     // one k-block per tap (ki,kj), K=32 channels
            const int ki = kb / 3, kj = kb % 3;
            bf16x8 a0 = *(const bf16x8*)(ap0 + kb * 32);
            bf16x8 a1 = *(const bf16x8*)(ap1 + kb * 32);
            #pragma unroll
            for (int mi = 0; mi < 7; ++mi) {
                // B[k = quad*8+j][n = laneM]: pixel px = mi*16+laneM+kj, staged row r+ki
                const bf16x8 bf = *(const bf16x8*)(&xs[((r + ki) * RPX + mi * 16 + laneM + kj) * XP + quad * 8]);
                acc[mi][0] = __builtin_amdgcn_mfma_f32_16x16x32_bf16(a0, bf, acc[mi][0], 0, 0, 0);
                acc[mi][1] = __builtin_amdgcn_mfma_f32_16x16x32_bf16(a1, bf, acc[mi][1], 0, 0, 0);
            }
        }

        // Epilogue: lane holds pixel px = mi*16+laneM, filters {fb..fb+3, fb+16..fb+19}.
        // Lane-pair swap (xor 1): instr 1 writes EVEN pixels' full 128B lines, instr 2 ODD.
        // nt stores: proven combination (R9 vs R7/R13).
        float* orow = out + (size_t)((b * HO + y0 + r) * WO) * NF;
        #pragma unroll
        for (int mi = 0; mi < 7; ++mi) {
            const int px = mi * 16 + laneM;
            const float ps = p_sq[r * 112 + px];
            f32x4 o0, o1;
            o0[0] = __expf(-bt0.x * (ps - 2.f * acc[mi][0][0] + cs0.x));
            o0[1] = __expf(-bt0.y * (ps - 2.f * acc[mi][0][1] + cs0.y));
            o0[2] = __expf(-bt0.z * (ps - 2.f * acc[mi][0][2] + cs0.z));
            o0[3] = __expf(-bt0.w * (ps - 2.f * acc[mi][0][3] + cs0.w));
            o1[0] = __expf(-bt1.x * (ps - 2.f * acc[mi][1][0] + cs1.x));
            o1[1] = __expf(-bt1.y * (ps - 2.f * acc[mi][1][1] + cs1.y));
            o1[2] = __expf(-bt1.z * (ps - 2.f * acc[mi][1][2] + cs1.z));
            o1[3] = __expf(-bt1.w * (ps - 2.f * acc[mi][1][3] + cs1.w));

            // even lane sends its ft1 half, odd lane sends its ft0 half; partner receives.
            f32x4 sendv = pl ? o0 : o1;
            f32x4 recv;
            recv[0] = __shfl_xor(sendv[0], 1);
            recv[1] = __shfl_xor(sendv[1], 1);
            recv[2] = __shfl_xor(sendv[2], 1);
            recv[3] = __shfl_xor(sendv[3], 1);
            const f32x4 v1 = pl ? recv : o0;   // even-pixel full 128B line
            const f32x4 v2 = pl ? o1 : recv;   // odd-pixel full line

            const int pxe = mi * 16 + (laneM & ~1);   // even pixel of the pair
            float* op1 = orow + (size_t)pxe * NF + fb + pl * 16;
            if (pxe < WO)
                __builtin_nontemporal_store(v1, (f32x4*)op1);
            if (pxe + 1 < WO)
                __builtin_nontemporal_store(v2, (f32x4*)(op1 + NF));
        }
    }
}

extern "C" void kernel_launch(void* const* d_in, const int* in_sizes, int n_in,
                              void* d_out, int out_size, void* d_ws, size_t ws_size,
                              hipStream_t stream) {
    const float* x    = (const float*)d_in[0];
    const float* ccs  = (const float*)d_in[1];
    const float* beta = (const float*)d_in[2];
    float* out = (float*)d_out;

    unsigned short* ccs_t = (unsigned short*)d_ws;                              // 128*288 bf16
    float* c_sq = (float*)((char*)d_ws + 128 * KD * sizeof(unsigned short));    // 128 f32

    rbf_prologue<<<144, 256, 0, stream>>>(ccs, ccs_t, c_sq);
    rbf_main<<<dim3(55, 32), 256, 0, stream>>>(x, ccs_t, c_sq, beta, out);
}